// Round 3
// baseline (164.998 us; speedup 1.0000x reference)
//
#include <hip/hip_runtime.h>

#define H 224
#define W 224
#define HW (224 * 224)
#define CIN 3
#define OCH 64
#define KG 7          // gaussian kernel
#define KC 5          // conv kernel
#define TLW 32        // tile width  (224/32 = 7 exact)
#define TLH 8         // tile height (224/8 = 28 exact)
// raw tile: (TLH+4+6) x (TLW+4+6) = 18 x 42, rows padded to 44
// mod tile: (TLH+4)   x (TLW+4)   = 12 x 36, rows padded to 40

// ---- tiny pre-pass: transpose weights (64,3,5,5) -> wT[75][64] so the 64
// per-k weights are contiguous (enables s_load_dwordx16 scalarization) ----
__global__ void transpose_w(const float* __restrict__ w, float* __restrict__ wT) {
    int i = blockIdx.x * 256 + threadIdx.x;
    if (i < OCH * CIN * KC * KC) {
        int oc = i / 75;
        int k = i - oc * 75;
        wT[k * OCH + oc] = w[i];
    }
}

__global__ __launch_bounds__(256) void fused_kernel(
    const float* __restrict__ in, const int* __restrict__ foa,
    const float* __restrict__ wT, float* __restrict__ out)
{
    __shared__ float s_raw[CIN][18][44];
    __shared__ float s_mod[CIN][12][40];

    int tx0 = blockIdx.x * TLW;
    int ty0 = blockIdx.y * TLH;
    int b   = blockIdx.z;
    int tid = threadIdx.x;

    const float* src = in + (size_t)b * CIN * HW;

    // ---- phase 0: stage raw input tile (zero-padded outside image) ----
    for (int i = tid; i < CIN * 18 * 42; i += 256) {
        int ch  = i / (18 * 42);
        int rem = i - ch * (18 * 42);
        int rr  = rem / 42;
        int cc  = rem - rr * 42;
        int gr = ty0 - 5 + rr;
        int gc = tx0 - 5 + cc;
        float v = 0.f;
        if ((unsigned)gr < H && (unsigned)gc < W)
            v = src[ch * HW + gr * W + gc];
        s_raw[ch][rr][cc] = v;
    }
    __syncthreads();

    // ---- phase 1: per-pixel Gaussian modulation of the 12x36 halo tile ----
    float fr = (float)foa[2 * b + 0];
    float fc = (float)foa[2 * b + 1];
    for (int p = tid; p < 12 * 36; p += 256) {
        int mr = p / 36;
        int mc = p - mr * 36;
        int gr = ty0 - 2 + mr;
        int gc = tx0 - 2 + mc;
        bool inimg = ((unsigned)gr < H) && ((unsigned)gc < W);

        float dr = (float)gr - fr, dc = (float)gc - fc;
        float dist = sqrtf(dr * dr + dc * dc) * 3.1567268e-3f; // 1/sqrt(224^2+224^2)
        float sigma = 0.01f + 0.99f * dist;
        float ae = -0.5f / (sigma * sigma);
        float e1 = __expf(ae);
        float e2 = e1 * e1;
        float e4 = e2 * e2;
        float e9 = e4 * e4 * e1;
        float pw[7] = {e9, e4, e1, 1.0f, e1, e4, e9};
        float S = 1.0f + 2.0f * (e1 + e4 + e9);
        float inv = 1.0f / (S * S);

        #pragma unroll
        for (int ch = 0; ch < CIN; ++ch) {
            float a = 0.f;
            #pragma unroll
            for (int ki = 0; ki < KG; ++ki) {
                const float* rp = &s_raw[ch][mr + ki][mc];
                float rs = 0.f;
                #pragma unroll
                for (int kj = 0; kj < KG; ++kj)
                    rs += pw[kj] * rp[kj];
                a += pw[ki] * rs;
            }
            s_mod[ch][mr][mc] = inimg ? a * inv : 0.f;
        }
    }
    __syncthreads();

    // ---- phase 2: 5x5 conv, 64 oc in TWO sequential passes of 32 ----
    // acc[32] keeps per-wave registers ~90 -> ~5 blocks/CU resident, and
    // per-kx weight chunk = 32 floats = 2x s_load_dwordx16 (fits SGPR budget
    // with prefetch instead of lgkmcnt(0) drains).
    int py  = tid >> 5;   // 0..7
    int pxl = tid & 31;   // 0..31

    #pragma unroll 1
    for (int pass = 0; pass < 2; ++pass) {
        const float* wbase = wT + pass * 32;   // wT[k][64], take 32-oc half

        float acc[32];
        #pragma unroll
        for (int oc = 0; oc < 32; ++oc) acc[oc] = 0.f;

        #pragma unroll 1
        for (int cky = 0; cky < CIN * KC; ++cky) {   // (ch,ky) pairs
            int ch = cky / 5;
            int ky = cky - ch * 5;
            const float* rp = &s_mod[ch][py + ky][pxl];
            float v[5] = {rp[0], rp[1], rp[2], rp[3], rp[4]};
            const float* wk = wbase + cky * 5 * OCH;    // block-uniform -> s_load
            #pragma unroll
            for (int kx = 0; kx < KC; ++kx) {
                const float* wp = wk + kx * OCH;
                #pragma unroll
                for (int oc = 0; oc < 32; ++oc)
                    acc[oc] = fmaf(v[kx], wp[oc], acc[oc]);
            }
        }

        // store this 32-oc half: 32 consecutive lanes -> 128B contiguous rows
        float* op = out + (((size_t)b * OCH + pass * 32) * H + (ty0 + py)) * W
                  + (tx0 + pxl);
        #pragma unroll
        for (int oc = 0; oc < 32; ++oc)
            op[(size_t)oc * HW] = acc[oc];
    }
}

extern "C" void kernel_launch(void* const* d_in, const int* in_sizes, int n_in,
                              void* d_out, int out_size, void* d_ws, size_t ws_size,
                              hipStream_t stream) {
    const float* input  = (const float*)d_in[0];   // (8,3,224,224) fp32
    const int*   foa    = (const int*)d_in[1];     // (8,2) int32
    const float* weight = (const float*)d_in[2];   // (64,3,5,5) fp32
    float* outp = (float*)d_out;                   // (8,64,224,224) fp32
    float* wT   = (float*)d_ws;                    // 75*64 floats = 19.2 KB

    transpose_w<<<(OCH * CIN * KC * KC + 255) / 256, 256, 0, stream>>>(weight, wT);

    dim3 grid(W / TLW, H / TLH, 8);   // 7 x 28 x 8 = 1568 blocks, exact tiling
    fused_kernel<<<grid, 256, 0, stream>>>(input, foa, wT, outp);
}

// Round 4
// 142.858 us; speedup vs baseline: 1.1550x; 1.1550x over previous
//
#include <hip/hip_runtime.h>

#define H 224
#define W 224
#define HW (224 * 224)
#define CIN 3
#define OCH 64
#define TLW 32
#define TLH 4
#define MODW 40   // s_mod row stride (floats)
#define RAWW 44   // s_raw row stride (floats)
#define STGW 136  // epilogue staging row stride (floats)

typedef __attribute__((ext_vector_type(8))) short short8;
typedef __attribute__((ext_vector_type(4))) float f32x4;

// round-to-nearest-even f32->bf16, packed pair (lo in low 16, hi in high 16)
__device__ __forceinline__ unsigned f2bf_pk(float lo, float hi) {
    unsigned a = __float_as_uint(lo), b = __float_as_uint(hi);
    a = (a + 0x7FFFu + ((a >> 16) & 1u)) >> 16;
    b = (b + 0x7FFFu + ((b >> 16) & 1u)) & 0xFFFF0000u;
    return a | b;
}

// ---- prepass: weights (64,3,5,5) fp32 -> bf16 B-fragment layout ----
// K reordered as k' = ch*32 + (ky*5+kx), zero-padded 25..31 per channel.
// Fragment (ks=ch, nt): lane holds B[k'=q*8+j][n=nt*16+(lane&15)], j=0..7.
__global__ void make_wfrag(const float* __restrict__ w, uint4* __restrict__ wB) {
    int t = threadIdx.x;
    if (t >= 768) return;
    int lane = t & 63;
    int nt = (t >> 6) & 3;
    int ks = t >> 8;          // == input channel
    int q = lane >> 4;
    int n = nt * 16 + (lane & 15);
    float v[8];
#pragma unroll
    for (int j = 0; j < 8; ++j) {
        int kk = q * 8 + j;
        v[j] = (kk < 25) ? w[n * 75 + ks * 25 + kk] : 0.f;
    }
    uint4 r;
    r.x = f2bf_pk(v[0], v[1]);
    r.y = f2bf_pk(v[2], v[3]);
    r.z = f2bf_pk(v[4], v[5]);
    r.w = f2bf_pk(v[6], v[7]);
    wB[(ks * 4 + nt) * 64 + lane] = r;
}

__global__ __launch_bounds__(256, 4) void fused_mfma(
    const float* __restrict__ in, const int* __restrict__ foa,
    const uint4* __restrict__ wB, float* __restrict__ out)
{
    __shared__ float s_mod[CIN][TLH + 4][MODW];              // 3840 B
    __shared__ __align__(16) char s_un[16 * STGW * 4];       // 8704 B: raw, then staging

    const int tid = threadIdx.x;
    const int tx0 = blockIdx.x * TLW;
    const int ty0 = blockIdx.y * TLH;
    const int b = blockIdx.z;

    // ---------- phase 0: stage raw tile (14 x 42 x 3, zero-padded) ----------
    {
        float (*s_raw)[TLH + 10][RAWW] = (float (*)[TLH + 10][RAWW])s_un;
        const float* src = in + (size_t)b * CIN * HW;
        for (int i = tid; i < CIN * (TLH + 10) * 42; i += 256) {
            int ch = i / ((TLH + 10) * 42);
            int rem = i - ch * ((TLH + 10) * 42);
            int rr = rem / 42;
            int cc = rem - rr * 42;
            int gr = ty0 - 5 + rr, gc = tx0 - 5 + cc;
            float v = 0.f;
            if ((unsigned)gr < H && (unsigned)gc < W) v = src[ch * HW + gr * W + gc];
            s_raw[ch][rr][cc] = v;
        }
    }
    __syncthreads();

    // ---------- phase 1: Gaussian modulation of 8 x 36 halo tile ----------
    {
        float (*s_raw)[TLH + 10][RAWW] = (float (*)[TLH + 10][RAWW])s_un;
        float fr = (float)foa[2 * b + 0], fc = (float)foa[2 * b + 1];
        for (int p = tid; p < (TLH + 4) * 36; p += 256) {
            int mr = p / 36, mc = p - mr * 36;
            int gr = ty0 - 2 + mr, gc = tx0 - 2 + mc;
            bool inimg = ((unsigned)gr < H) && ((unsigned)gc < W);
            float dr = (float)gr - fr, dc = (float)gc - fc;
            float dist = sqrtf(dr * dr + dc * dc) * 3.1567268e-3f; // 1/sqrt(224^2+224^2)
            float sigma = 0.01f + 0.99f * dist;
            float ae = -0.5f / (sigma * sigma);
            float e1 = __expf(ae);
            float e2 = e1 * e1, e4 = e2 * e2, e9 = e4 * e4 * e1;
            float pw[7] = {e9, e4, e1, 1.f, e1, e4, e9};
            float S = 1.f + 2.f * (e1 + e4 + e9);
            float inv = 1.f / (S * S);
#pragma unroll
            for (int ch = 0; ch < CIN; ++ch) {
                float a = 0.f;
#pragma unroll
                for (int ki = 0; ki < 7; ++ki) {
                    const float* rp = &s_raw[ch][mr + ki][mc];
                    float rs = 0.f;
#pragma unroll
                    for (int kj = 0; kj < 7; ++kj) rs += pw[kj] * rp[kj];
                    a += pw[ki] * rs;
                }
                s_mod[ch][mr][mc] = inimg ? a * inv : 0.f;
            }
        }
    }
    __syncthreads();

    // ---------- phase 2: MFMA GEMM  C[128px][64oc] = A[128][96] * B[96][64] ----------
    const int lane = tid & 63;
    const int wv = tid >> 6;   // wave 0..3
    const int q = lane >> 4;
    const int li = lane & 15;

    // per-lane A-fragment byte offsets within a channel plane of s_mod
    // (shared by all 3 k-steps via the +ks*1280 instruction offset)
    int aoff[8];
#pragma unroll
    for (int j = 0; j < 8; ++j) {
        int kk = q * 8 + j;
        int kkc = kk > 24 ? 24 : kk;
        int ky = (kkc * 13) >> 6;   // kkc/5 for 0..24
        int kx = kkc - ky * 5;
        aoff[j] = ky * (MODW * 4) + kx * 4;
    }
    int abase[2];
#pragma unroll
    for (int mt = 0; mt < 2; ++mt) {
        int mti = wv * 2 + mt;                  // m-tile 0..7 of the block
        int py = mti >> 1;                      // tile row 0..3
        int x = (mti & 1) * 16 + li;            // tile col 0..31
        abase[mt] = py * (MODW * 4) + x * 4;
    }
    const char* modb = (const char*)&s_mod[0][0][0];
    const bool qv = (q < 3);                    // q==3, j>=1 => k' padding (zero)

    f32x4 acc[2][4];
#pragma unroll
    for (int mt = 0; mt < 2; ++mt)
#pragma unroll
        for (int nt = 0; nt < 4; ++nt) acc[mt][nt] = (f32x4){0.f, 0.f, 0.f, 0.f};

#pragma unroll
    for (int ks = 0; ks < 3; ++ks) {            // k-step == input channel
        short8 bf[4];
#pragma unroll
        for (int nt = 0; nt < 4; ++nt) {
            union { uint4 u4; short8 s8; } cv;
            cv.u4 = wB[(ks * 4 + nt) * 64 + lane];   // coalesced 16B/lane, L2-hot
            bf[nt] = cv.s8;
        }
#pragma unroll
        for (int mt = 0; mt < 2; ++mt) {
            float v[8];
#pragma unroll
            for (int j = 0; j < 8; ++j) {
                float x = *(const float*)(modb + (abase[mt] + aoff[j] + ks * (8 * MODW * 4)));
                v[j] = (j == 0 || qv) ? x : 0.f;
            }
            union { unsigned u[4]; short8 s8; } af;
            af.u[0] = f2bf_pk(v[0], v[1]);
            af.u[1] = f2bf_pk(v[2], v[3]);
            af.u[2] = f2bf_pk(v[4], v[5]);
            af.u[3] = f2bf_pk(v[6], v[7]);
#pragma unroll
            for (int nt = 0; nt < 4; ++nt)
                acc[mt][nt] = __builtin_amdgcn_mfma_f32_16x16x32_bf16(
                    af.s8, bf[nt], acc[mt][nt], 0, 0, 0);
        }
    }

    // ---------- phase 3: epilogue — transpose via LDS, coalesced float4 stores ----------
    float (*stg)[STGW] = (float (*)[STGW])s_un;   // 16 oc x 128 px (stride 136)
#pragma unroll 1
    for (int nt = 0; nt < 4; ++nt) {
        __syncthreads();
#pragma unroll
        for (int mt = 0; mt < 2; ++mt) {
            int mti = wv * 2 + mt;
            int m0 = (mti >> 1) * 32 + (mti & 1) * 16 + q * 4;  // block px of reg r=0
            *(f32x4*)&stg[li][m0] = acc[mt][nt];                // ds_write_b128
        }
        __syncthreads();
#pragma unroll
        for (int i = 0; i < 2; ++i) {
            int ocl = (tid >> 5) + 8 * i;
            int m4 = (tid & 31);
            f32x4 val = *(const f32x4*)&stg[ocl][m4 * 4];
            int py = (m4 * 4) >> 5;
            int x = (m4 * 4) & 31;
            float* op = out + (((size_t)b * OCH + nt * 16 + ocl) * H + (ty0 + py)) * W
                      + tx0 + x;
            *(f32x4*)op = val;                                  // coalesced dwordx4
        }
    }
}

extern "C" void kernel_launch(void* const* d_in, const int* in_sizes, int n_in,
                              void* d_out, int out_size, void* d_ws, size_t ws_size,
                              hipStream_t stream) {
    const float* input  = (const float*)d_in[0];   // (8,3,224,224) fp32
    const int*   foa    = (const int*)d_in[1];     // (8,2) int32
    const float* weight = (const float*)d_in[2];   // (64,3,5,5) fp32
    float* outp = (float*)d_out;                   // (8,64,224,224) fp32
    uint4* wB   = (uint4*)d_ws;                    // 12 KB bf16 B-fragments

    make_wfrag<<<1, 768, 0, stream>>>(weight, wB);

    dim3 grid(W / TLW, H / TLH, 8);   // 7 x 56 x 8 = 3136 blocks
    fused_mfma<<<grid, 256, 0, stream>>>(input, foa, wB, outp);
}

// Round 5
// 137.287 us; speedup vs baseline: 1.2018x; 1.0406x over previous
//
#include <hip/hip_runtime.h>

#define H 224
#define W 224
#define HW (224 * 224)
#define CIN 3
#define OCH 64
#define PW 228            // padded plane width/height (2-halo on each side)
#define PHW (PW * PW)     // 51984
#define MTW 32            // modulate tile
#define MTH 16

typedef __attribute__((ext_vector_type(8))) short short8;
typedef __attribute__((ext_vector_type(4))) float f32x4;

// round-to-nearest-even f32->bf16, packed pair (lo in low 16, hi in high 16)
__device__ __forceinline__ unsigned f2bf_pk(float lo, float hi) {
    unsigned a = __float_as_uint(lo), b = __float_as_uint(hi);
    a = (a + 0x7FFFu + ((a >> 16) & 1u)) >> 16;
    b = (b + 0x7FFFu + ((b >> 16) & 1u)) & 0xFFFF0000u;
    return a | b;
}

// ---- prepass: weights (64,3,5,5) -> bf16 A-fragment layout ----
// A[m=oc][k'], k' = ks*32 + (ky*5+kx), zero-padded 25..31 per channel.
// Fragment (mt,ks): lane holds A[oc = mt*16+(lane&15)][k = q*8+j], j=0..7.
__global__ void make_wA(const float* __restrict__ w, uint4* __restrict__ wA) {
    int t = threadIdx.x;
    if (t >= 768) return;
    int lane = t & 63;
    int fi = t >> 6;            // 0..11 = mt*3+ks
    int mt = fi / 3, ks = fi - mt * 3;
    int q = lane >> 4;
    int oc = mt * 16 + (lane & 15);
    float v[8];
#pragma unroll
    for (int j = 0; j < 8; ++j) {
        int kk = q * 8 + j;
        v[j] = (kk < 25) ? w[oc * 75 + ks * 25 + kk] : 0.f;
    }
    uint4 r;
    r.x = f2bf_pk(v[0], v[1]);
    r.y = f2bf_pk(v[2], v[3]);
    r.z = f2bf_pk(v[4], v[5]);
    r.w = f2bf_pk(v[6], v[7]);
    wA[fi * 64 + lane] = r;
}

// ---- modulate: each output pixel computed exactly once, written into the
// zero-padded Pm buffer (8,3,228,228). Borders pre-zeroed by memset. ----
__global__ __launch_bounds__(256) void modulate(
    const float* __restrict__ in, const int* __restrict__ foa,
    float* __restrict__ Pm)
{
    __shared__ float s_raw[CIN][MTH + 6][40];   // 22 x 38 used, stride 40

    int tx0 = blockIdx.x * MTW;
    int ty0 = blockIdx.y * MTH;
    int b = blockIdx.z;
    int tid = threadIdx.x;

    const float* src = in + (size_t)b * CIN * HW;
    for (int i = tid; i < CIN * 22 * 38; i += 256) {
        int ch = i / (22 * 38);
        int rem = i - ch * (22 * 38);
        int rr = rem / 38;
        int cc = rem - rr * 38;
        int gr = ty0 - 3 + rr, gc = tx0 - 3 + cc;
        float v = 0.f;
        if ((unsigned)gr < H && (unsigned)gc < W) v = src[ch * HW + gr * W + gc];
        s_raw[ch][rr][cc] = v;
    }
    __syncthreads();

    float fr = (float)foa[2 * b + 0], fc = (float)foa[2 * b + 1];
    for (int p = tid; p < MTH * MTW; p += 256) {
        int r = p >> 5, c = p & 31;
        int gr = ty0 + r, gc = tx0 + c;       // always in-image (exact tiling)
        float dr = (float)gr - fr, dc = (float)gc - fc;
        float dist = sqrtf(dr * dr + dc * dc) * 3.1567268e-3f; // 1/sqrt(2*224^2)
        float sigma = 0.01f + 0.99f * dist;
        float ae = -0.5f / (sigma * sigma);
        float e1 = __expf(ae);
        float e2 = e1 * e1, e4 = e2 * e2, e9 = e4 * e4 * e1;
        float pw[7] = {e9, e4, e1, 1.f, e1, e4, e9};
        float S = 1.f + 2.f * (e1 + e4 + e9);
        float inv = 1.f / (S * S);
#pragma unroll
        for (int ch = 0; ch < CIN; ++ch) {
            float a = 0.f;
#pragma unroll
            for (int ki = 0; ki < 7; ++ki) {
                const float* rp = &s_raw[ch][r + ki][c];
                float rs = 0.f;
#pragma unroll
                for (int kj = 0; kj < 7; ++kj) rs += pw[kj] * rp[kj];
                a += pw[ki] * rs;
            }
            Pm[(size_t)(b * CIN + ch) * PHW + (size_t)(gr + 2) * PW + (gc + 2)] = a * inv;
        }
    }
}

// ---- GEMM: barrier-free, LDS-free. One wave = 16 px x 64 oc chunk. ----
// A = weights (m=oc) from wA; B = pixels gathered from padded Pm (L2-hot).
// D[row=oc=q*4+reg][col=px=lane&15] -> direct coalesced stores.
__global__ __launch_bounds__(256, 4) void gemm(
    const uint4* __restrict__ wA, const float* __restrict__ Pm,
    float* __restrict__ out)
{
    int tid = threadIdx.x;
    int lane = tid & 63;
    int wv = tid >> 6;
    int q = lane >> 4, li = lane & 15;

    int px0 = blockIdx.x * 16;            // 14 chunks across the row
    int py = blockIdx.y * 4 + wv;         // 56 row groups x 4 waves
    int b = blockIdx.z;

    // weight A-fragments (L1/L2-hot, 192 B per wave)
    short8 aw[4][3];
#pragma unroll
    for (int mt = 0; mt < 4; ++mt)
#pragma unroll
        for (int ks = 0; ks < 3; ++ks) {
            union { uint4 u4; short8 s8; } cv;
            cv.u4 = wA[(mt * 3 + ks) * 64 + lane];
            aw[mt][ks] = cv.s8;
        }

    // per-lane gather offsets (k = q*8+j; clamp padding taps to k=24: weight=0)
    int ofs[8];
#pragma unroll
    for (int j = 0; j < 8; ++j) {
        int kk = q * 8 + j;
        int kkc = kk > 24 ? 24 : kk;
        int ky = (kkc * 13) >> 6;         // kkc/5 for 0..24
        int kx = kkc - ky * 5;
        ofs[j] = ky * PW + kx;
    }

    // gather B fragments: lane li -> pixel px0+li, 8 taps per channel
    short8 bf[3];
#pragma unroll
    for (int ks = 0; ks < 3; ++ks) {
        const float* p = Pm + (size_t)(b * CIN + ks) * PHW + (size_t)py * PW + px0 + li;
        float v[8];
#pragma unroll
        for (int j = 0; j < 8; ++j) v[j] = p[ofs[j]];
        union { unsigned u[4]; short8 s8; } cv;
        cv.u[0] = f2bf_pk(v[0], v[1]);
        cv.u[1] = f2bf_pk(v[2], v[3]);
        cv.u[2] = f2bf_pk(v[4], v[5]);
        cv.u[3] = f2bf_pk(v[6], v[7]);
        bf[ks] = cv.s8;
    }

    f32x4 acc[4];
#pragma unroll
    for (int mt = 0; mt < 4; ++mt) acc[mt] = (f32x4){0.f, 0.f, 0.f, 0.f};
#pragma unroll
    for (int ks = 0; ks < 3; ++ks)
#pragma unroll
        for (int mt = 0; mt < 4; ++mt)
            acc[mt] = __builtin_amdgcn_mfma_f32_16x16x32_bf16(
                aw[mt][ks], bf[ks], acc[mt], 0, 0, 0);

    // store: oc = mt*16 + q*4 + r, px = px0 + li -> 64B segments per (q,r)
#pragma unroll
    for (int mt = 0; mt < 4; ++mt) {
#pragma unroll
        for (int r = 0; r < 4; ++r) {
            int oc = mt * 16 + q * 4 + r;
            out[(size_t)(b * OCH + oc) * HW + (size_t)py * W + px0 + li] = acc[mt][r];
        }
    }
}

extern "C" void kernel_launch(void* const* d_in, const int* in_sizes, int n_in,
                              void* d_out, int out_size, void* d_ws, size_t ws_size,
                              hipStream_t stream) {
    const float* input  = (const float*)d_in[0];   // (8,3,224,224) fp32
    const int*   foa    = (const int*)d_in[1];     // (8,2) int32
    const float* weight = (const float*)d_in[2];   // (64,3,5,5) fp32
    float* outp = (float*)d_out;                   // (8,64,224,224) fp32

    uint4* wA = (uint4*)d_ws;                                  // 12 KB
    float* Pm = (float*)((char*)d_ws + 16384);                 // 8*3*228*228 fp32 ~ 5 MB

    // zero the padded buffer (borders must be 0; interior overwritten by modulate)
    hipMemsetAsync(Pm, 0, (size_t)8 * CIN * PHW * sizeof(float), stream);

    make_wA<<<1, 768, 0, stream>>>(weight, wA);

    dim3 gridM(W / MTW, H / MTH, 8);    // 7 x 14 x 8 = 784 blocks
    modulate<<<gridM, 256, 0, stream>>>(input, foa, Pm);

    dim3 gridG(14, 56, 8);              // 16-px chunks x row-groups x batch
    gemm<<<gridG, 256, 0, stream>>>(wA, Pm, outp);
}